// Round 12
// baseline (136.104 us; speedup 1.0000x reference)
//
#include <hip/hip_runtime.h>
#include <stdint.h>

// Problem constants
#define DIMC   256
#define NHEADS 8
#define HD     32
#define BATCH  4
#define SEQ    2048
#define MTOT   (BATCH * SEQ)        // 8192 tokens
#define QKVN   (MTOT * HD * NHEADS) // 2097152 elements per q/k/v tensor
#define SCALE  0.17677669529663687f // 1/sqrt(32)
#define LOG2E  1.4426950408889634f
#define SCL2E  (SCALE * LOG2E)

typedef short bf16x8 __attribute__((ext_vector_type(8)));
typedef float f32x4  __attribute__((ext_vector_type(4)));

#if defined(__has_builtin)
#if __has_builtin(__builtin_amdgcn_exp2f)
#define EXP2F __builtin_amdgcn_exp2f
#else
#define EXP2F exp2f
#endif
#else
#define EXP2F exp2f
#endif

static __device__ __forceinline__ unsigned short f2bf(float f) {
    unsigned int u = __float_as_uint(f);
    u += 0x7fffu + ((u >> 16) & 1u);   // RNE
    return (unsigned short)(u >> 16);
}

static __device__ __forceinline__ unsigned int cvt2(float a, float b) {
#if defined(__has_builtin) && __has_builtin(__builtin_amdgcn_cvt_pk_bf16_f32)
    typedef __bf16 bf2 __attribute__((ext_vector_type(2)));
    bf2 v = __builtin_amdgcn_cvt_pk_bf16_f32(a, b);
    return __builtin_bit_cast(unsigned int, v);
#else
    return (unsigned int)f2bf(a) | ((unsigned int)f2bf(b) << 16);
#endif
}

// load 8 consecutive fp32 and pack to a bf16x8 fragment
static __device__ __forceinline__ bf16x8 ld8f_bf(const float* p) {
    float4 a0 = *(const float4*)p;
    float4 a1 = *(const float4*)(p + 4);
    uint4 pk;
    pk.x = cvt2(a0.x, a0.y); pk.y = cvt2(a0.z, a0.w);
    pk.z = cvt2(a1.x, a1.y); pk.w = cvt2(a1.z, a1.w);
    return __builtin_bit_cast(bf16x8, pk);
}

// ---------------------------------------------------------------------------
// QKV GEMM, A-traffic-minimal. Grid (3 supers x 64 m-blocks). Each block:
// one 256-col super (0=q,1=k,2=v; aligned with q/k/v boundaries) x 128 rows.
// All 4 n-tiles of the super's W staged ONCE in 128KB LDS (16B-aligned + XOR
// swizzle) -> A (fp32 x) is read exactly once per block: x traffic = 3x8 MB.
// q pre-scaled by SCALE*log2e; V stored transposed via in-LDS transpose.
// ---------------------------------------------------------------------------
__global__ __launch_bounds__(256) void gemm_qkv_kernel(
    const float* __restrict__ A,
    const float* __restrict__ W,
    const float* __restrict__ bias,
    unsigned short* __restrict__ qb,
    unsigned short* __restrict__ kb,
    unsigned short* __restrict__ vtb)
{
    __shared__ __align__(16) unsigned short FW[4][8][64][32];   // 128 KB

    const int t    = threadIdx.x;
    const int wave = t >> 6;
    const int lane = t & 63;
    const int cg   = lane & 15;
    const int quad = lane >> 4;
    const int sup  = blockIdx.x;          // 0 q, 1 k, 2 v
    const int m0   = blockIdx.y * 128;
    const int nb   = sup * 256;           // super's first column

    {   // stage the super's 256x256 W once (fp32 -> bf16, swizzled)
        int r  = t >> 2, cb = t & 3;
        int pc = (cb ^ ((r >> 1) & 3)) << 3;
        #pragma unroll
        for (int nt = 0; nt < 4; nt++)
            #pragma unroll
            for (int chunk = 0; chunk < 8; chunk++)
                *(bf16x8*)&FW[nt][chunk][r][pc] =
                    ld8f_bf(W + (size_t)(nb + nt * 64 + r) * 256 + chunk * 32 + cb * 8);
    }
    __syncthreads();

    const float* Arow = A + (size_t)(m0 + wave * 16 + cg) * 256 + quad * 8;
    const int rsw = ((cg >> 1) & 3);

    f32x4 acc[2][4][4];
    #pragma unroll
    for (int s = 0; s < 2; s++)
        #pragma unroll
        for (int nt = 0; nt < 4; nt++)
            #pragma unroll
            for (int c = 0; c < 4; c++) acc[s][nt][c] = (f32x4){0.f, 0.f, 0.f, 0.f};

    #pragma unroll
    for (int chunk = 0; chunk < 8; chunk++) {
        bf16x8 af[2];
        #pragma unroll
        for (int s = 0; s < 2; s++)
            af[s] = ld8f_bf(Arow + (size_t)s * 64 * 256 + chunk * 32);
        #pragma unroll
        for (int nt = 0; nt < 4; nt++)
            #pragma unroll
            for (int c = 0; c < 4; c++) {
                bf16x8 wf = *(const bf16x8*)&FW[nt][chunk][c * 16 + cg][(quad ^ rsw) << 3];
                #pragma unroll
                for (int s = 0; s < 2; s++)
                    acc[s][nt][c] = __builtin_amdgcn_mfma_f32_16x16x32_bf16(
                        af[s], wf, acc[s][nt][c], 0, 0, 0);
            }
    }

    if (sup < 2) {
        // q / k epilogue: C/D layout col = cg, row = quad*4 + reg
        unsigned short* dstb = (sup == 0) ? qb : kb;
        float scl = (sup == 0) ? SCL2E : 1.0f;
        #pragma unroll
        for (int s = 0; s < 2; s++)
            #pragma unroll
            for (int nt = 0; nt < 4; nt++)
                #pragma unroll
                for (int c = 0; c < 4; c++) {
                    int nl = nt * 64 + c * 16 + cg;   // 0..255
                    float bv = bias[nb + nl];
                    int h = nl >> 5, d = nl & 31;
                    #pragma unroll
                    for (int rr = 0; rr < 4; rr++) {
                        int m  = m0 + s * 64 + wave * 16 + quad * 4 + rr;
                        int b_ = m >> 11, nn = m & 2047;
                        dstb[((size_t)(b_ * NHEADS + h) * SEQ + nn) * HD + d] =
                            f2bf((acc[s][nt][c][rr] + bv) * scl);
                    }
                }
        return;
    }

    // V epilogue: transpose each 64n x 64m sub-tile through LDS (reuse FW)
    float (*TR)[68] = (float (*)[68])(void*)&FW[0][0][0][0];
    #pragma unroll
    for (int nt = 0; nt < 4; nt++) {
        #pragma unroll
        for (int s = 0; s < 2; s++) {
            __syncthreads();
            #pragma unroll
            for (int c = 0; c < 4; c++) {
                int l = c * 16 + cg;
                float bv = bias[nb + nt * 64 + l];
                float4 vv;
                vv.x = acc[s][nt][c][0] + bv; vv.y = acc[s][nt][c][1] + bv;
                vv.z = acc[s][nt][c][2] + bv; vv.w = acc[s][nt][c][3] + bv;
                *(float4*)__builtin_assume_aligned(&TR[l][wave * 16 + quad * 4], 16) = vv;
            }
            __syncthreads();
            int l  = t >> 2;                 // local n 0..63
            int mm = (t & 3) << 4;           // m offset 0,16,32,48
            int nl = nt * 64 + l;
            int h  = nl >> 5, d = nl & 31;
            int m  = m0 + s * 64 + mm;
            int b_ = m >> 11, nn = m & 2047;
            const float* tr = (const float*)__builtin_assume_aligned(&TR[l][mm], 16);
            float4 v0 = *(const float4*)(tr);
            float4 v1 = *(const float4*)(tr + 4);
            float4 v2 = *(const float4*)(tr + 8);
            float4 v3 = *(const float4*)(tr + 12);
            uint4 pk0, pk1;
            pk0.x = cvt2(v0.x, v0.y); pk0.y = cvt2(v0.z, v0.w);
            pk0.z = cvt2(v1.x, v1.y); pk0.w = cvt2(v1.z, v1.w);
            pk1.x = cvt2(v2.x, v2.y); pk1.y = cvt2(v2.z, v2.w);
            pk1.z = cvt2(v3.x, v3.y); pk1.w = cvt2(v3.z, v3.w);
            unsigned short* dst = vtb + ((size_t)((b_ * NHEADS + h) * HD + d)) * SEQ + nn;
            *(uint4*)dst       = pk0;
            *(uint4*)(dst + 8) = pk1;
        }
    }
}

// ---------------------------------------------------------------------------
// Projection GEMM, A-traffic-minimal: full 256-col W staged once in 128KB
// LDS; grid = 128 m-blocks of 64 rows -> ao read exactly once (4 MB).
// ---------------------------------------------------------------------------
__global__ __launch_bounds__(256) void gemm_proj_kernel(
    const unsigned short* __restrict__ A,
    const float* __restrict__ W,
    const float* __restrict__ bias,
    float* __restrict__ outf)
{
    __shared__ __align__(16) unsigned short FW[4][8][64][32];   // 128 KB

    const int t    = threadIdx.x;
    const int wave = t >> 6;
    const int lane = t & 63;
    const int cg   = lane & 15;
    const int quad = lane >> 4;
    const int m0   = blockIdx.y * 64;

    {
        int r  = t >> 2, cb = t & 3;
        int pc = (cb ^ ((r >> 1) & 3)) << 3;
        #pragma unroll
        for (int nt = 0; nt < 4; nt++)
            #pragma unroll
            for (int chunk = 0; chunk < 8; chunk++)
                *(bf16x8*)&FW[nt][chunk][r][pc] =
                    ld8f_bf(W + (size_t)(nt * 64 + r) * 256 + chunk * 32 + cb * 8);
    }
    __syncthreads();

    const unsigned short* Arow = A + (size_t)(m0 + wave * 16 + cg) * 256 + quad * 8;
    const int rsw = ((cg >> 1) & 3);

    f32x4 acc[4][4];
    #pragma unroll
    for (int nt = 0; nt < 4; nt++)
        #pragma unroll
        for (int c = 0; c < 4; c++) acc[nt][c] = (f32x4){0.f, 0.f, 0.f, 0.f};

    #pragma unroll
    for (int chunk = 0; chunk < 8; chunk++) {
        bf16x8 af = *(const bf16x8*)(Arow + chunk * 32);
        #pragma unroll
        for (int nt = 0; nt < 4; nt++)
            #pragma unroll
            for (int c = 0; c < 4; c++) {
                bf16x8 wf = *(const bf16x8*)&FW[nt][chunk][c * 16 + cg][(quad ^ rsw) << 3];
                acc[nt][c] = __builtin_amdgcn_mfma_f32_16x16x32_bf16(af, wf, acc[nt][c], 0, 0, 0);
            }
    }

    #pragma unroll
    for (int nt = 0; nt < 4; nt++)
        #pragma unroll
        for (int c = 0; c < 4; c++) {
            int n = nt * 64 + c * 16 + cg;
            float bv = bias[n];
            #pragma unroll
            for (int rr = 0; rr < 4; rr++) {
                int m = m0 + wave * 16 + quad * 4 + rr;
                outf[(size_t)m * 256 + n] = acc[nt][c][rr] + bv;
            }
        }
}

// ---------------------------------------------------------------------------
// Key-split MFMA flash attention (unchanged from round 11; proven).
// ---------------------------------------------------------------------------
__global__ __launch_bounds__(256) void attn_mfma_kernel(
    const unsigned short* __restrict__ Q,
    const unsigned short* __restrict__ K,
    const unsigned short* __restrict__ Vt,
    const float* __restrict__ table,
    unsigned short* __restrict__ AO)
{
    __shared__ __align__(16) unsigned short PL[4][64][72];   // 36 KB
    __shared__ __align__(16) unsigned short KA7[7][32];      // 448 B bias rows

    const int t    = threadIdx.x;
    const int wave = t >> 6;
    const int lane = t & 63;
    const int cg   = lane & 15;
    const int quad = lane >> 4;

    const int bid = blockIdx.x;
    const int qt  = bid & 31;
    const int bh  = bid >> 5;
    const int b   = bh >> 3;
    const int h   = bh & 7;
    const int q0  = qt * 64;

    if (t < 224) {
        int r = t >> 5, c = t & 31;
        float v = (c < 7) ? table[c - r + 6] * LOG2E : 0.f;
        KA7[r][c] = f2bf(v);
    }
    __syncthreads();

    const unsigned short* Kbase = K  + (size_t)bh * (SEQ * HD);
    const unsigned short* Vbase = Vt + (size_t)bh * (SEQ * HD);

    bf16x8 qf[4], qfa[4];
    #pragma unroll
    for (int qi = 0; qi < 4; qi++) {
        qf[qi]  = *(const bf16x8*)(Q + (size_t)bh * (SEQ * HD) +
                                   (size_t)(q0 + qi * 16 + cg) * HD + quad * 8);
        int p = (q0 + qi * 16 + cg) % 7;
        #pragma unroll
        for (int i = 0; i < 8; i++)
            qfa[qi][i] = (quad == 0 && i == p) ? (short)0x3F80 : (short)0;
    }

    bf16x8 ones;
    #pragma unroll
    for (int i = 0; i < 8; i++) ones[i] = (short)0x3F80;

    f32x4 o[4][2], ol[4];
    #pragma unroll
    for (int qi = 0; qi < 4; qi++) {
        o[qi][0] = (f32x4){0.f, 0.f, 0.f, 0.f};
        o[qi][1] = (f32x4){0.f, 0.f, 0.f, 0.f};
        ol[qi]   = (f32x4){0.f, 0.f, 0.f, 0.f};
    }

    const int kstart = wave * (SEQ / 4);
    int kb7[4];
    #pragma unroll
    for (int jt = 0; jt < 4; jt++) kb7[jt] = (kstart + jt * 16 + cg) % 7;

    #pragma unroll 2
    for (int jj = 0; jj < SEQ / 4; jj += 64) {
        const int j0 = kstart + jj;

        bf16x8 kf[4], kfa[4];
        #pragma unroll
        for (int jt = 0; jt < 4; jt++) {
            kf[jt]  = *(const bf16x8*)(Kbase + (size_t)(j0 + jt * 16 + cg) * HD + quad * 8);
            kfa[jt] = *(const bf16x8*)&KA7[kb7[jt]][quad * 8];
        }
        bf16x8 vf[2][2];
        #pragma unroll
        for (int kt = 0; kt < 2; kt++)
            #pragma unroll
            for (int dt = 0; dt < 2; dt++)
                vf[kt][dt] = *(const bf16x8*)(Vbase + (size_t)(dt * 16 + cg) * SEQ +
                                              j0 + kt * 32 + quad * 8);

        #pragma unroll
        for (int half = 0; half < 2; half++) {
            f32x4 s[2][4];
            #pragma unroll
            for (int qh = 0; qh < 2; qh++) {
                int qi = half * 2 + qh;
                #pragma unroll
                for (int jt = 0; jt < 4; jt++) {
                    s[qh][jt] = __builtin_amdgcn_mfma_f32_16x16x32_bf16(
                        kfa[jt], qfa[qi], (f32x4){0.f, 0.f, 0.f, 0.f}, 0, 0, 0);
                    s[qh][jt] = __builtin_amdgcn_mfma_f32_16x16x32_bf16(
                        kf[jt], qf[qi], s[qh][jt], 0, 0, 0);
                }
            }
            #pragma unroll
            for (int qh = 0; qh < 2; qh++) {
                int qi = half * 2 + qh;
                #pragma unroll
                for (int jt = 0; jt < 4; jt++) {
                    float p0 = EXP2F(s[qh][jt][0]);
                    float p1 = EXP2F(s[qh][jt][1]);
                    float p2 = EXP2F(s[qh][jt][2]);
                    float p3 = EXP2F(s[qh][jt][3]);
                    uint2 w;
                    w.x = cvt2(p0, p1);
                    w.y = cvt2(p2, p3);
                    *(uint2*)&PL[wave][qi * 16 + cg][jt * 16 + quad * 4] = w;
                }
            }
        }
        __builtin_amdgcn_s_waitcnt(0xC07F);

        #pragma unroll
        for (int qi = 0; qi < 4; qi++) {
            bf16x8 pa0 = *(const bf16x8*)&PL[wave][qi * 16 + cg][quad * 8];
            bf16x8 pa1 = *(const bf16x8*)&PL[wave][qi * 16 + cg][32 + quad * 8];
            o[qi][0] = __builtin_amdgcn_mfma_f32_16x16x32_bf16(pa0, vf[0][0], o[qi][0], 0, 0, 0);
            o[qi][0] = __builtin_amdgcn_mfma_f32_16x16x32_bf16(pa1, vf[1][0], o[qi][0], 0, 0, 0);
            o[qi][1] = __builtin_amdgcn_mfma_f32_16x16x32_bf16(pa0, vf[0][1], o[qi][1], 0, 0, 0);
            o[qi][1] = __builtin_amdgcn_mfma_f32_16x16x32_bf16(pa1, vf[1][1], o[qi][1], 0, 0, 0);
            ol[qi]   = __builtin_amdgcn_mfma_f32_16x16x32_bf16(pa0, ones, ol[qi], 0, 0, 0);
            ol[qi]   = __builtin_amdgcn_mfma_f32_16x16x32_bf16(pa1, ones, ol[qi], 0, 0, 0);
        }

        #pragma unroll
        for (int jt = 0; jt < 4; jt++)
            kb7[jt] = (kb7[jt] == 6) ? 0 : kb7[jt] + 1;
    }

    __builtin_amdgcn_s_waitcnt(0xC07F);
    float* OPw = (float*)&PL[wave][0][0];
    #pragma unroll
    for (int qi = 0; qi < 4; qi++) {
        #pragma unroll
        for (int dt = 0; dt < 2; dt++)
            #pragma unroll
            for (int rr = 0; rr < 4; rr++)
                OPw[(qi * 16 + quad * 4 + rr) * 33 + dt * 16 + cg] = o[qi][dt][rr];
        if (cg == 0) {
            #pragma unroll
            for (int rr = 0; rr < 4; rr++)
                OPw[(qi * 16 + quad * 4 + rr) * 33 + 32] = ol[qi][rr];
        }
    }
    __syncthreads();

    {
        int q  = t >> 2;
        int d0 = (t & 3) << 3;
        float l = 0.f;
        float ov[8];
        #pragma unroll
        for (int i = 0; i < 8; i++) ov[i] = 0.f;
        #pragma unroll
        for (int w = 0; w < 4; w++) {
            const float* OPx = (const float*)&PL[w][0][0];
            l += OPx[q * 33 + 32];
            #pragma unroll
            for (int i = 0; i < 8; i++) ov[i] += OPx[q * 33 + d0 + i];
        }
        float inv = 1.f / l;
        unsigned short pk[8];
        #pragma unroll
        for (int i = 0; i < 8; i += 2) {
            unsigned int u = cvt2(ov[i] * inv, ov[i + 1] * inv);
            pk[i]     = (unsigned short)(u & 0xffffu);
            pk[i + 1] = (unsigned short)(u >> 16);
        }
        *(uint4*)(AO + ((size_t)(b * SEQ + q0 + q)) * DIMC + h * HD + d0) = *(const uint4*)pk;
    }
}

// ---------------------------------------------------------------------------
extern "C" void kernel_launch(void* const* d_in, const int* in_sizes, int n_in,
                              void* d_out, int out_size, void* d_ws, size_t ws_size,
                              hipStream_t stream) {
    const float* x      = (const float*)d_in[0]; // (4,2048,256)
    const float* qkv_w  = (const float*)d_in[1]; // (768,256)
    const float* qkv_b  = (const float*)d_in[2]; // (768)
    const float* proj_w = (const float*)d_in[3]; // (256,256)
    const float* proj_b = (const float*)d_in[4]; // (256)
    const float* table  = (const float*)d_in[5]; // (104)
    float* out = (float*)d_out;                  // (4,2048,256) fp32

    unsigned short* ws   = (unsigned short*)d_ws;
    unsigned short* qb   = ws;                         // [bh][seq][32] bf16 (pre-scaled)
    unsigned short* kb   = qb  + (size_t)QKVN;
    unsigned short* vtb  = kb  + (size_t)QKVN;         // [bh][32][seq]
    unsigned short* ao   = vtb + (size_t)QKVN;         // [B*seq][256]

    // 1) QKV GEMM: 3 q/k/v-aligned supers x 64 m-blocks; x read once/block
    gemm_qkv_kernel<<<dim3(3, 64), 256, 0, stream>>>(
        x, qkv_w, qkv_b, qb, kb, vtb);

    // 2) key-split MFMA flash attention (unchanged)
    attn_mfma_kernel<<<dim3(BATCH * NHEADS * (SEQ / 64)), 256, 0, stream>>>(
        qb, kb, vtb, table, ao);

    // 3) output projection: full-N W resident; ao read once
    gemm_proj_kernel<<<dim3(1, 128), 256, 0, stream>>>(
        ao, proj_w, proj_b, out);
}

// Round 13
// 131.995 us; speedup vs baseline: 1.0311x; 1.0311x over previous
//
#include <hip/hip_runtime.h>
#include <stdint.h>

// Problem constants
#define DIMC   256
#define NHEADS 8
#define HD     32
#define BATCH  4
#define SEQ    2048
#define MTOT   (BATCH * SEQ)        // 8192 tokens
#define QKVN   (MTOT * HD * NHEADS) // 2097152 elements per q/k/v tensor
#define SCALE  0.17677669529663687f // 1/sqrt(32)
#define LOG2E  1.4426950408889634f
#define SCL2E  (SCALE * LOG2E)

typedef short bf16x8 __attribute__((ext_vector_type(8)));
typedef float f32x4  __attribute__((ext_vector_type(4)));

#if defined(__has_builtin)
#if __has_builtin(__builtin_amdgcn_exp2f)
#define EXP2F __builtin_amdgcn_exp2f
#else
#define EXP2F exp2f
#endif
#else
#define EXP2F exp2f
#endif

static __device__ __forceinline__ unsigned short f2bf(float f) {
    unsigned int u = __float_as_uint(f);
    u += 0x7fffu + ((u >> 16) & 1u);   // RNE
    return (unsigned short)(u >> 16);
}

static __device__ __forceinline__ unsigned int cvt2(float a, float b) {
#if defined(__has_builtin) && __has_builtin(__builtin_amdgcn_cvt_pk_bf16_f32)
    typedef __bf16 bf2 __attribute__((ext_vector_type(2)));
    bf2 v = __builtin_amdgcn_cvt_pk_bf16_f32(a, b);
    return __builtin_bit_cast(unsigned int, v);
#else
    return (unsigned int)f2bf(a) | ((unsigned int)f2bf(b) << 16);
#endif
}

// load 8 consecutive fp32 and pack to a bf16x8 fragment
static __device__ __forceinline__ bf16x8 ld8f_bf(const float* p) {
    float4 a0 = *(const float4*)p;
    float4 a1 = *(const float4*)(p + 4);
    uint4 pk;
    pk.x = cvt2(a0.x, a0.y); pk.y = cvt2(a0.z, a0.w);
    pk.z = cvt2(a1.x, a1.y); pk.w = cvt2(a1.z, a1.w);
    return __builtin_bit_cast(bf16x8, pk);
}

// ---------------------------------------------------------------------------
// QKV GEMM, XCD-locality-swizzled. 768 blocks (1D); dispatch round-robins
// bid%8 across XCDs, so we map: xcd = bid&7, j = bid>>3 (0..95),
// m-tile = xcd*8 + (j&7)  (128 rows each), n-tile = j>>3 (0..11, 64 cols).
// => each XCD touches 8 m-tiles (1 MB fp32 x) + W (786 KB) -> both fit its
// 4 MB L2, so the 12x A re-reads and 64x W re-reads become L2 hits.
// W tile (64x256) staged once in 32 KB LDS (16B-aligned + XOR swizzle).
// q pre-scaled by SCALE*log2e; V stored transposed via in-LDS transpose.
// ---------------------------------------------------------------------------
__global__ __launch_bounds__(256) void gemm_qkv_kernel(
    const float* __restrict__ A,
    const float* __restrict__ W,
    const float* __restrict__ bias,
    unsigned short* __restrict__ qb,
    unsigned short* __restrict__ kb,
    unsigned short* __restrict__ vtb)
{
    __shared__ __align__(16) unsigned short FW[8][64][32];   // 32 KB

    const int t    = threadIdx.x;
    const int wave = t >> 6;
    const int lane = t & 63;
    const int cg   = lane & 15;
    const int quad = lane >> 4;

    const int bid = blockIdx.x;
    const int xcd = bid & 7;
    const int j   = bid >> 3;             // 0..95
    const int m0  = (xcd * 8 + (j & 7)) * 128;
    const int n0  = (j >> 3) * 64;        // 0..704

    {   // stage the 64x256 W tile once (fp32 -> bf16, swizzled)
        int r  = t >> 2, cb = t & 3;
        int pc = (cb ^ ((r >> 1) & 3)) << 3;
        #pragma unroll
        for (int chunk = 0; chunk < 8; chunk++)
            *(bf16x8*)&FW[chunk][r][pc] =
                ld8f_bf(W + (size_t)(n0 + r) * 256 + chunk * 32 + cb * 8);
    }
    __syncthreads();

    const float* Arow = A + (size_t)(m0 + wave * 16 + cg) * 256 + quad * 8;
    const int rsw = ((cg >> 1) & 3);   // read swizzle term

    f32x4 acc[2][4];
    #pragma unroll
    for (int s = 0; s < 2; s++)
        #pragma unroll
        for (int c = 0; c < 4; c++) acc[s][c] = (f32x4){0.f, 0.f, 0.f, 0.f};

    #pragma unroll
    for (int chunk = 0; chunk < 8; chunk++) {
        bf16x8 wf[4];
        #pragma unroll
        for (int c = 0; c < 4; c++)
            wf[c] = *(const bf16x8*)&FW[chunk][c * 16 + cg][(quad ^ rsw) << 3];
        #pragma unroll
        for (int s = 0; s < 2; s++) {
            bf16x8 af = ld8f_bf(Arow + (size_t)s * 64 * 256 + chunk * 32);
            #pragma unroll
            for (int c = 0; c < 4; c++)
                acc[s][c] = __builtin_amdgcn_mfma_f32_16x16x32_bf16(af, wf[c], acc[s][c], 0, 0, 0);
        }
    }

    if (n0 >= 512) {
        // pure-V tile: transpose through LDS (reuse FW memory as f32[64][68])
        float (*TR)[68] = (float (*)[68])(void*)&FW[0][0][0];
        #pragma unroll
        for (int s = 0; s < 2; s++) {
            __syncthreads();   // FW reads / previous TR pass done
            #pragma unroll
            for (int c = 0; c < 4; c++) {
                int l = c * 16 + cg;              // local n
                float bv = bias[n0 + l];
                float4 vv;
                vv.x = acc[s][c][0] + bv; vv.y = acc[s][c][1] + bv;
                vv.z = acc[s][c][2] + bv; vv.w = acc[s][c][3] + bv;
                *(float4*)__builtin_assume_aligned(&TR[l][wave * 16 + quad * 4], 16) = vv;
            }
            __syncthreads();
            int l  = t >> 2;                      // local n 0..63
            int mm = (t & 3) << 4;                // m offset 0,16,32,48
            int n  = n0 + l;
            int h  = (n >> 5) & 7;
            int d  = n & 31;
            int b_ = m0 >> 11;
            int nn = (m0 & 2047) + s * 64 + mm;
            const float* tr = (const float*)__builtin_assume_aligned(&TR[l][mm], 16);
            float4 v0 = *(const float4*)(tr);
            float4 v1 = *(const float4*)(tr + 4);
            float4 v2 = *(const float4*)(tr + 8);
            float4 v3 = *(const float4*)(tr + 12);
            uint4 pk0, pk1;
            pk0.x = cvt2(v0.x, v0.y); pk0.y = cvt2(v0.z, v0.w);
            pk0.z = cvt2(v1.x, v1.y); pk0.w = cvt2(v1.z, v1.w);
            pk1.x = cvt2(v2.x, v2.y); pk1.y = cvt2(v2.z, v2.w);
            pk1.z = cvt2(v3.x, v3.y); pk1.w = cvt2(v3.z, v3.w);
            unsigned short* dst = vtb + ((size_t)((b_ * NHEADS + h) * HD + d)) * SEQ + nn;
            *(uint4*)dst       = pk0;
            *(uint4*)(dst + 8) = pk1;
        }
        return;
    }

    #pragma unroll
    for (int s = 0; s < 2; s++) {
        #pragma unroll
        for (int c = 0; c < 4; c++) {
            int n = n0 + c * 16 + cg;
            float bv = bias[n];
            int which = n >> 8;        // 0 q, 1 k
            int h     = (n >> 5) & 7;
            int d     = n & 31;
            #pragma unroll
            for (int rr = 0; rr < 4; rr++) {
                int m = m0 + s * 64 + wave * 16 + quad * 4 + rr;
                float val = acc[s][c][rr] + bv;
                int b_ = m >> 11;
                int nn = m & 2047;
                int bh = b_ * NHEADS + h;
                if (which == 0)
                    qb[((size_t)bh * SEQ + nn) * HD + d] = f2bf(val * SCL2E);
                else
                    kb[((size_t)bh * SEQ + nn) * HD + d] = f2bf(val);
            }
        }
    }
}

// ---------------------------------------------------------------------------
// Projection GEMM, XCD-locality-swizzled. 512 blocks: xcd = bid&7,
// j = bid>>3 (0..63), m-tile = xcd*16 + (j&15) (64 rows), n-tile = j>>4
// (0..3). Per XCD: 512 KB ao + 256 KB W -> L2-resident re-reads.
// ---------------------------------------------------------------------------
__global__ __launch_bounds__(256) void gemm_proj_kernel(
    const unsigned short* __restrict__ A,
    const float* __restrict__ W,
    const float* __restrict__ bias,
    float* __restrict__ outf)
{
    __shared__ __align__(16) unsigned short FW[8][64][32];   // 32 KB

    const int t    = threadIdx.x;
    const int wave = t >> 6;
    const int lane = t & 63;
    const int cg   = lane & 15;
    const int quad = lane >> 4;

    const int bid = blockIdx.x;
    const int xcd = bid & 7;
    const int j   = bid >> 3;             // 0..63
    const int m0  = (xcd * 16 + (j & 15)) * 64;
    const int n0  = (j >> 4) * 64;        // 0..192

    {
        int r  = t >> 2, cb = t & 3;
        int pc = (cb ^ ((r >> 1) & 3)) << 3;
        #pragma unroll
        for (int chunk = 0; chunk < 8; chunk++)
            *(bf16x8*)&FW[chunk][r][pc] =
                ld8f_bf(W + (size_t)(n0 + r) * 256 + chunk * 32 + cb * 8);
    }
    __syncthreads();

    const unsigned short* Arow = A + (size_t)(m0 + wave * 16 + cg) * 256 + quad * 8;
    const int rsw = ((cg >> 1) & 3);

    f32x4 acc[4];
    #pragma unroll
    for (int c = 0; c < 4; c++) acc[c] = (f32x4){0.f, 0.f, 0.f, 0.f};

    #pragma unroll
    for (int chunk = 0; chunk < 8; chunk++) {
        bf16x8 af = *(const bf16x8*)(Arow + chunk * 32);
        bf16x8 wf[4];
        #pragma unroll
        for (int c = 0; c < 4; c++)
            wf[c] = *(const bf16x8*)&FW[chunk][c * 16 + cg][(quad ^ rsw) << 3];
        #pragma unroll
        for (int c = 0; c < 4; c++)
            acc[c] = __builtin_amdgcn_mfma_f32_16x16x32_bf16(af, wf[c], acc[c], 0, 0, 0);
    }

    #pragma unroll
    for (int c = 0; c < 4; c++) {
        int n = n0 + c * 16 + cg;
        float bv = bias[n];
        #pragma unroll
        for (int rr = 0; rr < 4; rr++) {
            int m = m0 + wave * 16 + quad * 4 + rr;
            outf[(size_t)m * 256 + n] = acc[c][rr] + bv;
        }
    }
}

// ---------------------------------------------------------------------------
// Key-split MFMA flash attention (proven r11/r12 kernel; KA7 rows padded to
// 40 shorts = 80B stride to de-alias the row-gather banks).
// ---------------------------------------------------------------------------
__global__ __launch_bounds__(256) void attn_mfma_kernel(
    const unsigned short* __restrict__ Q,
    const unsigned short* __restrict__ K,
    const unsigned short* __restrict__ Vt,
    const float* __restrict__ table,
    unsigned short* __restrict__ AO)
{
    __shared__ __align__(16) unsigned short PL[4][64][72];   // 36 KB
    __shared__ __align__(16) unsigned short KA7[7][40];      // 560 B bias rows

    const int t    = threadIdx.x;
    const int wave = t >> 6;
    const int lane = t & 63;
    const int cg   = lane & 15;
    const int quad = lane >> 4;

    const int bid = blockIdx.x;
    const int qt  = bid & 31;
    const int bh  = bid >> 5;
    const int b   = bh >> 3;
    const int h   = bh & 7;
    const int q0  = qt * 64;

    if (t < 224) {
        int r = t >> 5, c = t & 31;
        float v = (c < 7) ? table[c - r + 6] * LOG2E : 0.f;
        KA7[r][c] = f2bf(v);
    }
    __syncthreads();

    const unsigned short* Kbase = K  + (size_t)bh * (SEQ * HD);
    const unsigned short* Vbase = Vt + (size_t)bh * (SEQ * HD);

    bf16x8 qf[4], qfa[4];
    #pragma unroll
    for (int qi = 0; qi < 4; qi++) {
        qf[qi]  = *(const bf16x8*)(Q + (size_t)bh * (SEQ * HD) +
                                   (size_t)(q0 + qi * 16 + cg) * HD + quad * 8);
        int p = (q0 + qi * 16 + cg) % 7;
        #pragma unroll
        for (int i = 0; i < 8; i++)
            qfa[qi][i] = (quad == 0 && i == p) ? (short)0x3F80 : (short)0;
    }

    bf16x8 ones;
    #pragma unroll
    for (int i = 0; i < 8; i++) ones[i] = (short)0x3F80;

    f32x4 o[4][2], ol[4];
    #pragma unroll
    for (int qi = 0; qi < 4; qi++) {
        o[qi][0] = (f32x4){0.f, 0.f, 0.f, 0.f};
        o[qi][1] = (f32x4){0.f, 0.f, 0.f, 0.f};
        ol[qi]   = (f32x4){0.f, 0.f, 0.f, 0.f};
    }

    const int kstart = wave * (SEQ / 4);
    int kb7[4];
    #pragma unroll
    for (int jt = 0; jt < 4; jt++) kb7[jt] = (kstart + jt * 16 + cg) % 7;

    #pragma unroll 2
    for (int jj = 0; jj < SEQ / 4; jj += 64) {
        const int j0 = kstart + jj;

        bf16x8 kf[4], kfa[4];
        #pragma unroll
        for (int jt = 0; jt < 4; jt++) {
            kf[jt]  = *(const bf16x8*)(Kbase + (size_t)(j0 + jt * 16 + cg) * HD + quad * 8);
            kfa[jt] = *(const bf16x8*)&KA7[kb7[jt]][quad * 8];
        }
        bf16x8 vf[2][2];
        #pragma unroll
        for (int kt = 0; kt < 2; kt++)
            #pragma unroll
            for (int dt = 0; dt < 2; dt++)
                vf[kt][dt] = *(const bf16x8*)(Vbase + (size_t)(dt * 16 + cg) * SEQ +
                                              j0 + kt * 32 + quad * 8);

        #pragma unroll
        for (int half = 0; half < 2; half++) {
            f32x4 s[2][4];
            #pragma unroll
            for (int qh = 0; qh < 2; qh++) {
                int qi = half * 2 + qh;
                #pragma unroll
                for (int jt = 0; jt < 4; jt++) {
                    s[qh][jt] = __builtin_amdgcn_mfma_f32_16x16x32_bf16(
                        kfa[jt], qfa[qi], (f32x4){0.f, 0.f, 0.f, 0.f}, 0, 0, 0);
                    s[qh][jt] = __builtin_amdgcn_mfma_f32_16x16x32_bf16(
                        kf[jt], qf[qi], s[qh][jt], 0, 0, 0);
                }
            }
            #pragma unroll
            for (int qh = 0; qh < 2; qh++) {
                int qi = half * 2 + qh;
                #pragma unroll
                for (int jt = 0; jt < 4; jt++) {
                    float p0 = EXP2F(s[qh][jt][0]);
                    float p1 = EXP2F(s[qh][jt][1]);
                    float p2 = EXP2F(s[qh][jt][2]);
                    float p3 = EXP2F(s[qh][jt][3]);
                    uint2 w;
                    w.x = cvt2(p0, p1);
                    w.y = cvt2(p2, p3);
                    *(uint2*)&PL[wave][qi * 16 + cg][jt * 16 + quad * 4] = w;
                }
            }
        }
        __builtin_amdgcn_s_waitcnt(0xC07F);

        #pragma unroll
        for (int qi = 0; qi < 4; qi++) {
            bf16x8 pa0 = *(const bf16x8*)&PL[wave][qi * 16 + cg][quad * 8];
            bf16x8 pa1 = *(const bf16x8*)&PL[wave][qi * 16 + cg][32 + quad * 8];
            o[qi][0] = __builtin_amdgcn_mfma_f32_16x16x32_bf16(pa0, vf[0][0], o[qi][0], 0, 0, 0);
            o[qi][0] = __builtin_amdgcn_mfma_f32_16x16x32_bf16(pa1, vf[1][0], o[qi][0], 0, 0, 0);
            o[qi][1] = __builtin_amdgcn_mfma_f32_16x16x32_bf16(pa0, vf[0][1], o[qi][1], 0, 0, 0);
            o[qi][1] = __builtin_amdgcn_mfma_f32_16x16x32_bf16(pa1, vf[1][1], o[qi][1], 0, 0, 0);
            ol[qi]   = __builtin_amdgcn_mfma_f32_16x16x32_bf16(pa0, ones, ol[qi], 0, 0, 0);
            ol[qi]   = __builtin_amdgcn_mfma_f32_16x16x32_bf16(pa1, ones, ol[qi], 0, 0, 0);
        }

        #pragma unroll
        for (int jt = 0; jt < 4; jt++)
            kb7[jt] = (kb7[jt] == 6) ? 0 : kb7[jt] + 1;
    }

    __builtin_amdgcn_s_waitcnt(0xC07F);
    float* OPw = (float*)&PL[wave][0][0];
    #pragma unroll
    for (int qi = 0; qi < 4; qi++) {
        #pragma unroll
        for (int dt = 0; dt < 2; dt++)
            #pragma unroll
            for (int rr = 0; rr < 4; rr++)
                OPw[(qi * 16 + quad * 4 + rr) * 33 + dt * 16 + cg] = o[qi][dt][rr];
        if (cg == 0) {
            #pragma unroll
            for (int rr = 0; rr < 4; rr++)
                OPw[(qi * 16 + quad * 4 + rr) * 33 + 32] = ol[qi][rr];
        }
    }
    __syncthreads();

    {
        int q  = t >> 2;
        int d0 = (t & 3) << 3;
        float l = 0.f;
        float ov[8];
        #pragma unroll
        for (int i = 0; i < 8; i++) ov[i] = 0.f;
        #pragma unroll
        for (int w = 0; w < 4; w++) {
            const float* OPx = (const float*)&PL[w][0][0];
            l += OPx[q * 33 + 32];
            #pragma unroll
            for (int i = 0; i < 8; i++) ov[i] += OPx[q * 33 + d0 + i];
        }
        float inv = 1.f / l;
        unsigned short pk[8];
        #pragma unroll
        for (int i = 0; i < 8; i += 2) {
            unsigned int u = cvt2(ov[i] * inv, ov[i + 1] * inv);
            pk[i]     = (unsigned short)(u & 0xffffu);
            pk[i + 1] = (unsigned short)(u >> 16);
        }
        *(uint4*)(AO + ((size_t)(b * SEQ + q0 + q)) * DIMC + h * HD + d0) = *(const uint4*)pk;
    }
}

// ---------------------------------------------------------------------------
extern "C" void kernel_launch(void* const* d_in, const int* in_sizes, int n_in,
                              void* d_out, int out_size, void* d_ws, size_t ws_size,
                              hipStream_t stream) {
    const float* x      = (const float*)d_in[0]; // (4,2048,256)
    const float* qkv_w  = (const float*)d_in[1]; // (768,256)
    const float* qkv_b  = (const float*)d_in[2]; // (768)
    const float* proj_w = (const float*)d_in[3]; // (256,256)
    const float* proj_b = (const float*)d_in[4]; // (256)
    const float* table  = (const float*)d_in[5]; // (104)
    float* out = (float*)d_out;                  // (4,2048,256) fp32

    unsigned short* ws   = (unsigned short*)d_ws;
    unsigned short* qb   = ws;                         // [bh][seq][32] bf16 (pre-scaled)
    unsigned short* kb   = qb  + (size_t)QKVN;
    unsigned short* vtb  = kb  + (size_t)QKVN;         // [bh][32][seq]
    unsigned short* ao   = vtb + (size_t)QKVN;         // [B*seq][256]

    // 1) QKV GEMM (XCD-swizzled; x+W L2-resident per XCD)
    gemm_qkv_kernel<<<dim3(768), 256, 0, stream>>>(
        x, qkv_w, qkv_b, qb, kb, vtb);

    // 2) key-split MFMA flash attention (unchanged + KA7 pad)
    attn_mfma_kernel<<<dim3(BATCH * NHEADS * (SEQ / 64)), 256, 0, stream>>>(
        qb, kb, vtb, table, ao);

    // 3) output projection (XCD-swizzled)
    gemm_proj_kernel<<<dim3(512), 256, 0, stream>>>(
        ao, proj_w, proj_b, out);
}